// Round 1
// 966.415 us; speedup vs baseline: 1.2692x; 1.2692x over previous
//
#include <hip/hip_runtime.h>
#include <hip/hip_fp16.h>

#define B_   2
#define S_   4096
#define H_   16
#define DK_  128
#define DV_  128
#define CK_  64
#define NC_  (S_/CK_)            // 64 chunks per sequence
#define QSCALE 0.08838834764831845f   // 128^-0.5

#define DOT4(a,b) ((a).x*(b).x + (a).y*(b).y + (a).z*(b).z + (a).w*(b).w)

static __device__ __forceinline__ unsigned short f2bf(float x) {
    unsigned u = __float_as_uint(x);
    unsigned r = u + 0x7fffu + ((u >> 16) & 1u);
    return (unsigned short)(r >> 16);
}
static __device__ __forceinline__ float bf2f(unsigned short h) {
    return __uint_as_float(((unsigned)h) << 16);
}
static __device__ __forceinline__ float4 h4tof4(const __half* p) {
    float2 f01 = __half22float2(*(const __half2*)p);
    float2 f23 = __half22float2(*(const __half2*)(p + 2));
    return make_float4(f01.x, f01.y, f23.x, f23.y);
}
static __device__ __forceinline__ void f4toh4(__half* p, float4 v) {
    *(__half2*)p       = __floats2half2_rn(v.x, v.y);
    *(__half2*)(p + 2) = __floats2half2_rn(v.z, v.w);
}

// ---------------- Phase 1: per-chunk (parallel over 2048 chunks) ----------------
// LDS = 74752 B -> 2 blocks/CU (was 88064 -> 1 block/CU).
// kn holds RAW k, XOR-swizzled 4-col groups (col ^ (row&28)) to kill 8-way conflicts.
// rsqrt/beta/exp(g) row/col factors folded into epilogues via cL/cR (no scale passes).
// Unit-lower inverse done blocked: 16x16 diag (column-parallel) + 2 doubling levels
// -> 6 barriers instead of 126.
__global__ __launch_bounds__(256) void dr_phase1(
    const float* __restrict__ Q, const float* __restrict__ K,
    const float* __restrict__ V, const float* __restrict__ G,
    const float* __restrict__ Bt,
    unsigned short* __restrict__ Uw, unsigned short* __restrict__ KCDw,
    unsigned short* __restrict__ ATTNw,
    float* __restrict__ RQw, float* __restrict__ RKw, float* __restrict__ EGw)
{
    __shared__ float kn[64][132];                 // raw k, swizzled
    __shared__ __align__(16) __half bufh[64][136]; // v*beta, then raw q (f16)
    __shared__ float T[64][68];
    __shared__ float tmp[32][36];                 // blocked-inverse scratch
    __shared__ float bet[64], rn[64], epos[64], eneg[64], cL[64], cR[64];

    const int tid = threadIdx.x;
    const int cid = blockIdx.x;
    const int n   = cid & (NC_ - 1);
    const int bh  = cid >> 6;
    const int h   = bh & (H_ - 1);
    const int b   = bh >> 4;
    const int rowbase = (b*S_ + n*CK_)*H_ + h;

    // A: stage raw K (swizzled); wave0: shfl-scan of g, exps, beta
    #pragma unroll
    for (int i = 0; i < 8; ++i) {
        int idx4 = tid + 256*i;
        int r = idx4 >> 5, c0 = (idx4 & 31) << 2;
        *(float4*)&kn[r][c0 ^ (r & 28)] =
            *(const float4*)(K + (size_t)(rowbase + r*H_)*DK_ + c0);
    }
    if (tid < 64) {
        float g = G[rowbase + tid*H_];
        #pragma unroll
        for (int off = 1; off < 64; off <<= 1) {
            float o = __shfl_up(g, off, 64);
            if (tid >= off) g += o;
        }
        float ep = expf(g);
        epos[tid] = ep;
        eneg[tid] = expf(-g);
        bet[tid]  = Bt[rowbase + tid*H_];
        if (tid == 63) EGw[cid] = ep;
    }
    __syncthreads();

    // B: stage v*beta -> f16; k row norms -> rn, cL, cR, RK
    #pragma unroll
    for (int i = 0; i < 8; ++i) {
        int idx4 = tid + 256*i;
        int r = idx4 >> 5, c0 = (idx4 & 31) << 2;
        float bb = bet[r];
        float4 vv = *(const float4*)(V + (size_t)(rowbase + r*H_)*DV_ + c0);
        vv.x *= bb; vv.y *= bb; vv.z *= bb; vv.w *= bb;
        f4toh4(&bufh[r][c0], vv);
    }
    if (tid < 64) {
        const int xr = tid & 28;
        float s = 0.f;
        #pragma unroll
        for (int c = 0; c < 128; c += 4) { float4 x = *(float4*)&kn[tid][c ^ xr]; s += DOT4(x,x); }
        float r_ = rsqrtf(s + 1e-6f);
        rn[tid] = r_;
        RKw[cid*64 + tid] = r_*epos[63]*eneg[tid];
        cL[tid] = bet[tid]*epos[tid]*r_;
        cR[tid] = eneg[tid]*r_;
    }
    __syncthreads();

    // C: T = -strict_lower( cL(i)*cR(j) * (kraw_i . kraw_j) )
    {
        const int i0 = (tid >> 4) << 2, j0 = (tid & 15) << 2;
        const int xi = i0 & 28, xj = j0 & 28;
        float acc[4][4] = {};
        if (j0 <= i0) {
            for (int c = 0; c < 128; c += 4) {
                float4 a0 = *(float4*)&kn[i0  ][c ^ xi], a1 = *(float4*)&kn[i0+1][c ^ xi];
                float4 a2 = *(float4*)&kn[i0+2][c ^ xi], a3 = *(float4*)&kn[i0+3][c ^ xi];
                float4 b0 = *(float4*)&kn[j0  ][c ^ xj], b1 = *(float4*)&kn[j0+1][c ^ xj];
                float4 b2 = *(float4*)&kn[j0+2][c ^ xj], b3 = *(float4*)&kn[j0+3][c ^ xj];
                acc[0][0]+=DOT4(a0,b0); acc[0][1]+=DOT4(a0,b1); acc[0][2]+=DOT4(a0,b2); acc[0][3]+=DOT4(a0,b3);
                acc[1][0]+=DOT4(a1,b0); acc[1][1]+=DOT4(a1,b1); acc[1][2]+=DOT4(a1,b2); acc[1][3]+=DOT4(a1,b3);
                acc[2][0]+=DOT4(a2,b0); acc[2][1]+=DOT4(a2,b1); acc[2][2]+=DOT4(a2,b2); acc[2][3]+=DOT4(a2,b3);
                acc[3][0]+=DOT4(a3,b0); acc[3][1]+=DOT4(a3,b1); acc[3][2]+=DOT4(a3,b2); acc[3][3]+=DOT4(a3,b3);
            }
        }
        #pragma unroll
        for (int x = 0; x < 4; ++x) {
            float fi = cL[i0+x];
            #pragma unroll
            for (int y = 0; y < 4; ++y) {
                int i = i0+x, j = j0+y;
                T[i][j] = (i > j) ? (-fi*cR[j]*acc[x][y]) : 0.f;
            }
        }
    }
    __syncthreads();

    // D1: copy diagonal 16x16 blocks (original -A) into tmp
    {
        float* tf = &tmp[0][0];
        for (int t = tid; t < 1024; t += 256) {
            int d = t >> 8, i = (t >> 4) & 15, j = t & 15;
            tf[t] = T[(d<<4) + i][(d<<4) + j];
        }
    }
    __syncthreads();
    // D2: invert each diagonal block in place, one thread per (block, column)
    if (tid < 64) {
        const float* Ad = &tmp[0][0] + ((tid >> 4) << 8);
        const int j = tid & 15, R = (tid >> 4) << 4;
        for (int i = j+1; i < 16; ++i) {
            float x = Ad[(i<<4) + j];
            for (int l = j+1; l < i; ++l) x += Ad[(i<<4) + l] * T[R+l][R+j];
            T[R+i][R+j] = x;
        }
    }
    __syncthreads();
    // D3: 16 -> 32 (two pairs). X21 = (I+X22) * T21 * (I+X11)
    {
        const int p = tid >> 7, rem = tid & 127, i = rem >> 3, j0 = (rem & 7) << 1;
        const int bb2 = p << 5;
        // P = T21 * (I + X11) -> tmp
        float x0 = T[bb2+16+i][bb2+j0], x1 = T[bb2+16+i][bb2+j0+1];
        for (int l = j0+1; l < 16; ++l) {
            float a = T[bb2+16+i][bb2+l];
            x0 += a * T[bb2+l][bb2+j0];
            if (l > j0+1) x1 += a * T[bb2+l][bb2+j0+1];
        }
        tmp[(p<<4)+i][j0] = x0; tmp[(p<<4)+i][j0+1] = x1;
        __syncthreads();
        // X21 = (I + X22) * P -> T21 region
        float y0 = tmp[(p<<4)+i][j0], y1 = tmp[(p<<4)+i][j0+1];
        for (int l = 0; l < i; ++l) {
            float a = T[bb2+16+i][bb2+16+l];
            y0 += a * tmp[(p<<4)+l][j0];
            y1 += a * tmp[(p<<4)+l][j0+1];
        }
        T[bb2+16+i][bb2+j0] = y0; T[bb2+16+i][bb2+j0+1] = y1;
    }
    __syncthreads();
    // D4: 32 -> 64
    {
        const int i = tid >> 3, j0 = (tid & 7) << 2;
        // P = T21 * (I + X11) -> tmp
        float x0 = T[32+i][j0], x1 = T[32+i][j0+1], x2 = T[32+i][j0+2], x3 = T[32+i][j0+3];
        for (int l = j0+1; l < 32; ++l) {
            float a = T[32+i][l];
            x0 += a * T[l][j0];
            if (l > j0+1) x1 += a * T[l][j0+1];
            if (l > j0+2) x2 += a * T[l][j0+2];
            if (l > j0+3) x3 += a * T[l][j0+3];
        }
        tmp[i][j0] = x0; tmp[i][j0+1] = x1; tmp[i][j0+2] = x2; tmp[i][j0+3] = x3;
        __syncthreads();
        // X21 = (I + X22) * P -> T21 region
        float y0 = tmp[i][j0], y1 = tmp[i][j0+1], y2 = tmp[i][j0+2], y3 = tmp[i][j0+3];
        for (int l = 0; l < i; ++l) {
            float a = T[32+i][32+l];
            y0 += a * tmp[l][j0];   y1 += a * tmp[l][j0+1];
            y2 += a * tmp[l][j0+2]; y3 += a * tmp[l][j0+3];
        }
        T[32+i][j0] = y0; T[32+i][j0+1] = y1; T[32+i][j0+2] = y2; T[32+i][j0+3] = y3;
    }
    __syncthreads();

    // E: U = (I+T) @ (v*beta),  KCD = (I+T) @ (k*beta*exp(gcs))  -> bf16
    {
        unsigned short* Up = Uw + (size_t)cid*(CK_*DV_);
        for (int tt = tid; tt < 512; tt += 256) {
            const int i0 = (tt >> 5) << 2, c0 = (tt & 31) << 2;
            float4 acc[4];
            #pragma unroll
            for (int x = 0; x < 4; ++x) acc[x] = h4tof4(&bufh[i0+x][c0]);
            for (int j0 = 0; j0 <= i0; j0 += 4) {
                float4 t0 = *(float4*)&T[i0][j0],   t1 = *(float4*)&T[i0+1][j0];
                float4 t2 = *(float4*)&T[i0+2][j0], t3 = *(float4*)&T[i0+3][j0];
                float4 b0 = h4tof4(&bufh[j0][c0]),   b1 = h4tof4(&bufh[j0+1][c0]);
                float4 b2 = h4tof4(&bufh[j0+2][c0]), b3 = h4tof4(&bufh[j0+3][c0]);
                acc[0].x += t0.x*b0.x + t0.y*b1.x + t0.z*b2.x + t0.w*b3.x;
                acc[0].y += t0.x*b0.y + t0.y*b1.y + t0.z*b2.y + t0.w*b3.y;
                acc[0].z += t0.x*b0.z + t0.y*b1.z + t0.z*b2.z + t0.w*b3.z;
                acc[0].w += t0.x*b0.w + t0.y*b1.w + t0.z*b2.w + t0.w*b3.w;
                acc[1].x += t1.x*b0.x + t1.y*b1.x + t1.z*b2.x + t1.w*b3.x;
                acc[1].y += t1.x*b0.y + t1.y*b1.y + t1.z*b2.y + t1.w*b3.y;
                acc[1].z += t1.x*b0.z + t1.y*b1.z + t1.z*b2.z + t1.w*b3.z;
                acc[1].w += t1.x*b0.w + t1.y*b1.w + t1.z*b2.w + t1.w*b3.w;
                acc[2].x += t2.x*b0.x + t2.y*b1.x + t2.z*b2.x + t2.w*b3.x;
                acc[2].y += t2.x*b0.y + t2.y*b1.y + t2.z*b2.y + t2.w*b3.y;
                acc[2].z += t2.x*b0.z + t2.y*b1.z + t2.z*b2.z + t2.w*b3.z;
                acc[2].w += t2.x*b0.w + t2.y*b1.w + t2.z*b2.w + t2.w*b3.w;
                acc[3].x += t3.x*b0.x + t3.y*b1.x + t3.z*b2.x + t3.w*b3.x;
                acc[3].y += t3.x*b0.y + t3.y*b1.y + t3.z*b2.y + t3.w*b3.y;
                acc[3].z += t3.x*b0.z + t3.y*b1.z + t3.z*b2.z + t3.w*b3.z;
                acc[3].w += t3.x*b0.w + t3.y*b1.w + t3.z*b2.w + t3.w*b3.w;
            }
            #pragma unroll
            for (int x = 0; x < 4; ++x) {
                ushort4 o; o.x = f2bf(acc[x].x); o.y = f2bf(acc[x].y);
                o.z = f2bf(acc[x].z); o.w = f2bf(acc[x].w);
                *(ushort4*)(Up + (i0+x)*DV_ + c0) = o;
            }
        }
        unsigned short* Kp = KCDw + (size_t)cid*(CK_*DK_);
        for (int tt = tid; tt < 512; tt += 256) {
            const int i0 = (tt >> 5) << 2, c0 = (tt & 31) << 2;
            const int xi = i0 & 28;
            float4 acc[4];
            #pragma unroll
            for (int x = 0; x < 4; ++x) {
                float wi = cL[i0+x];
                float4 kv = *(float4*)&kn[i0+x][c0 ^ xi];
                acc[x].x = kv.x*wi; acc[x].y = kv.y*wi; acc[x].z = kv.z*wi; acc[x].w = kv.w*wi;
            }
            for (int j0 = 0; j0 <= i0; j0 += 4) {
                const int xj = j0 & 28;
                float w0 = cL[j0], w1 = cL[j0+1], w2 = cL[j0+2], w3 = cL[j0+3];
                float4 t0 = *(float4*)&T[i0][j0],   t1 = *(float4*)&T[i0+1][j0];
                float4 t2 = *(float4*)&T[i0+2][j0], t3 = *(float4*)&T[i0+3][j0];
                float4 b0 = *(float4*)&kn[j0  ][c0 ^ xj], b1 = *(float4*)&kn[j0+1][c0 ^ xj];
                float4 b2 = *(float4*)&kn[j0+2][c0 ^ xj], b3 = *(float4*)&kn[j0+3][c0 ^ xj];
                b0.x*=w0; b0.y*=w0; b0.z*=w0; b0.w*=w0;
                b1.x*=w1; b1.y*=w1; b1.z*=w1; b1.w*=w1;
                b2.x*=w2; b2.y*=w2; b2.z*=w2; b2.w*=w2;
                b3.x*=w3; b3.y*=w3; b3.z*=w3; b3.w*=w3;
                acc[0].x += t0.x*b0.x + t0.y*b1.x + t0.z*b2.x + t0.w*b3.x;
                acc[0].y += t0.x*b0.y + t0.y*b1.y + t0.z*b2.y + t0.w*b3.y;
                acc[0].z += t0.x*b0.z + t0.y*b1.z + t0.z*b2.z + t0.w*b3.z;
                acc[0].w += t0.x*b0.w + t0.y*b1.w + t0.z*b2.w + t0.w*b3.w;
                acc[1].x += t1.x*b0.x + t1.y*b1.x + t1.z*b2.x + t1.w*b3.x;
                acc[1].y += t1.x*b0.y + t1.y*b1.y + t1.z*b2.y + t1.w*b3.y;
                acc[1].z += t1.x*b0.z + t1.y*b1.z + t1.z*b2.z + t1.w*b3.z;
                acc[1].w += t1.x*b0.w + t1.y*b1.w + t1.z*b2.w + t1.w*b3.w;
                acc[2].x += t2.x*b0.x + t2.y*b1.x + t2.z*b2.x + t2.w*b3.x;
                acc[2].y += t2.x*b0.y + t2.y*b1.y + t2.z*b2.y + t2.w*b3.y;
                acc[2].z += t2.x*b0.z + t2.y*b1.z + t2.z*b2.z + t2.w*b3.z;
                acc[2].w += t2.x*b0.w + t2.y*b1.w + t2.z*b2.w + t2.w*b3.w;
                acc[3].x += t3.x*b0.x + t3.y*b1.x + t3.z*b2.x + t3.w*b3.x;
                acc[3].y += t3.x*b0.y + t3.y*b1.y + t3.z*b2.y + t3.w*b3.y;
                acc[3].z += t3.x*b0.z + t3.y*b1.z + t3.z*b2.z + t3.w*b3.z;
                acc[3].w += t3.x*b0.w + t3.y*b1.w + t3.z*b2.w + t3.w*b3.w;
            }
            #pragma unroll
            for (int x = 0; x < 4; ++x) {
                ushort4 o; o.x = f2bf(acc[x].x); o.y = f2bf(acc[x].y);
                o.z = f2bf(acc[x].z); o.w = f2bf(acc[x].w);
                *(ushort4*)(Kp + (i0+x)*DK_ + c0) = o;
            }
        }
    }
    __syncthreads();

    // F: stage raw q -> f16 (scale folded into epilogue)
    #pragma unroll
    for (int i = 0; i < 8; ++i) {
        int idx4 = tid + 256*i;
        int r = idx4 >> 5, c0 = (idx4 & 31) << 2;
        f4toh4(&bufh[r][c0], *(const float4*)(Q + (size_t)(rowbase + r*H_)*DK_ + c0));
    }
    __syncthreads();
    // G: q row norms (QSCALE folded); RQ
    if (tid < 64) {
        float s = 0.f;
        #pragma unroll
        for (int c = 0; c < 128; c += 4) { float4 x = h4tof4(&bufh[tid][c]); s += DOT4(x,x); }
        float r_ = rsqrtf(s + 1e-6f)*QSCALE;
        rn[tid] = r_;
        RQw[cid*64 + tid] = r_*epos[tid];
    }
    __syncthreads();

    // H: attn = tril(q@k^T * decay) -> bf16   (row factor rn_q*epos, col factor cR)
    {
        unsigned short* Ap = ATTNw + (size_t)cid*(CK_*CK_);
        const int i0 = (tid >> 4) << 2, j0 = (tid & 15) << 2;
        const int xj = j0 & 28;
        float acc[4][4] = {};
        if (j0 <= i0) {
            for (int c = 0; c < 128; c += 4) {
                float4 a0 = h4tof4(&bufh[i0  ][c]), a1 = h4tof4(&bufh[i0+1][c]);
                float4 a2 = h4tof4(&bufh[i0+2][c]), a3 = h4tof4(&bufh[i0+3][c]);
                float4 b0 = *(float4*)&kn[j0  ][c ^ xj], b1 = *(float4*)&kn[j0+1][c ^ xj];
                float4 b2 = *(float4*)&kn[j0+2][c ^ xj], b3 = *(float4*)&kn[j0+3][c ^ xj];
                acc[0][0]+=DOT4(a0,b0); acc[0][1]+=DOT4(a0,b1); acc[0][2]+=DOT4(a0,b2); acc[0][3]+=DOT4(a0,b3);
                acc[1][0]+=DOT4(a1,b0); acc[1][1]+=DOT4(a1,b1); acc[1][2]+=DOT4(a1,b2); acc[1][3]+=DOT4(a1,b3);
                acc[2][0]+=DOT4(a2,b0); acc[2][1]+=DOT4(a2,b1); acc[2][2]+=DOT4(a2,b2); acc[2][3]+=DOT4(a2,b3);
                acc[3][0]+=DOT4(a3,b0); acc[3][1]+=DOT4(a3,b1); acc[3][2]+=DOT4(a3,b2); acc[3][3]+=DOT4(a3,b3);
            }
        }
        #pragma unroll
        for (int x = 0; x < 4; ++x) {
            ushort4 o;
            int i = i0+x;
            float fi = rn[i]*epos[i];
            float v0 = (j0   <= i) ? acc[x][0]*fi*cR[j0]   : 0.f;
            float v1 = (j0+1 <= i) ? acc[x][1]*fi*cR[j0+1] : 0.f;
            float v2 = (j0+2 <= i) ? acc[x][2]*fi*cR[j0+2] : 0.f;
            float v3 = (j0+3 <= i) ? acc[x][3]*fi*cR[j0+3] : 0.f;
            o.x = f2bf(v0); o.y = f2bf(v1); o.z = f2bf(v2); o.w = f2bf(v3);
            *(ushort4*)(Ap + i*CK_ + j0) = o;
        }
    }
}

// ---------------- Phase 2: state recurrence only (256 blocks = bh x 8 v-slices) ----------------
__global__ __launch_bounds__(256) void dr_phase2(
    const float* __restrict__ K,
    const unsigned short* __restrict__ Uw, const unsigned short* __restrict__ KCDw,
    const float* __restrict__ RKw, const float* __restrict__ EGw,
    unsigned short* __restrict__ STw)
{
    __shared__ float kc[64][132];    // kcd fp32
    __shared__ float kd[64][132];    // k_norm * exp(g_last - gcs)
    __shared__ float stT[16][132];   // state^T slice: stT[v][k]
    __shared__ float vn[64][20];     // v_new slice

    const int tid = threadIdx.x;
    const int vs = blockIdx.x & 7, bh = blockIdx.x >> 3;
    const int h = bh & (H_-1), b = bh >> 4;
    const int v0 = vs*16;

    for (int i = tid; i < 16*132; i += 256) (&stT[0][0])[i] = 0.f;
    __syncthreads();

    const int rg = tid >> 3, wg = tid & 7;
    const int r0 = rg*2, w0v = wg*2;            // vn tile
    const int wq = tid >> 5, kq = tid & 31;
    const int w0s = wq*2, k0s = kq*4;           // state tile
    const int srow = tid >> 4, scol = (tid & 15)*8;   // ST store map

    for (int n = 0; n < NC_; ++n) {
        const int cid = bh*NC_ + n;
        const int rowbase = (b*S_ + n*CK_)*H_ + h;

        // store state entering chunk n (pre-update) for phase 3
        {
            float4 s0 = *(float4*)&stT[srow][scol];
            float4 s1 = *(float4*)&stT[srow][scol+4];
            ushort4 p0, p1;
            p0.x=f2bf(s0.x); p0.y=f2bf(s0.y); p0.z=f2bf(s0.z); p0.w=f2bf(s0.w);
            p1.x=f2bf(s1.x); p1.y=f2bf(s1.y); p1.z=f2bf(s1.z); p1.w=f2bf(s1.w);
            size_t base = ((size_t)cid*128 + v0 + srow)*128 + scol;
            *(ushort4*)(STw + base)     = p0;
            *(ushort4*)(STw + base + 4) = p1;
        }
        const float a_dec = EGw[cid];
        // load kcd (bf16->fp32) and kd = K*RK'
        {
            const uint2* kcp = (const uint2*)(KCDw + (size_t)cid*8192);
            #pragma unroll
            for (int i = 0; i < 8; ++i) {
                int idx4 = tid + 256*i;
                int r = idx4 >> 5, c0 = (idx4 & 31)*4;
                uint2 pv = kcp[idx4];
                float4 f;
                f.x = bf2f((unsigned short)(pv.x & 0xffff));
                f.y = bf2f((unsigned short)(pv.x >> 16));
                f.z = bf2f((unsigned short)(pv.y & 0xffff));
                f.w = bf2f((unsigned short)(pv.y >> 16));
                *(float4*)&kc[r][c0] = f;
                float rk = RKw[cid*64 + r];
                float4 kv = *(const float4*)(K + (size_t)(rowbase + r*H_)*DK_ + c0);
                kv.x *= rk; kv.y *= rk; kv.z *= rk; kv.w *= rk;
                *(float4*)&kd[r][c0] = kv;
            }
        }
        // u accumulator init (2x2 tile)
        float u00,u01,u10,u11;
        {
            const unsigned short* up = Uw + (size_t)cid*8192;
            unsigned uv0 = *(const unsigned*)(up + r0*128 + v0 + w0v);
            unsigned uv1 = *(const unsigned*)(up + (r0+1)*128 + v0 + w0v);
            u00 = bf2f((unsigned short)(uv0 & 0xffff)); u01 = bf2f((unsigned short)(uv0 >> 16));
            u10 = bf2f((unsigned short)(uv1 & 0xffff)); u11 = bf2f((unsigned short)(uv1 >> 16));
        }
        __syncthreads();

        // vn = u - kc @ stT^T
        {
            float s00=u00, s01=u01, s10=u10, s11=u11;
            for (int k0 = 0; k0 < 128; k0 += 4) {
                float4 a0 = *(float4*)&kc[r0][k0];
                float4 a1 = *(float4*)&kc[r0+1][k0];
                float4 b0 = *(float4*)&stT[w0v][k0];
                float4 b1 = *(float4*)&stT[w0v+1][k0];
                s00 -= DOT4(a0,b0); s01 -= DOT4(a0,b1);
                s10 -= DOT4(a1,b0); s11 -= DOT4(a1,b1);
            }
            vn[r0][w0v] = s00;   vn[r0][w0v+1] = s01;
            vn[r0+1][w0v] = s10; vn[r0+1][w0v+1] = s11;
        }
        __syncthreads();

        // stT = a*stT + vn^T @ kd   (2w x 4k tile, in place)
        {
            float4 acc0 = *(float4*)&stT[w0s][k0s];
            float4 acc1 = *(float4*)&stT[w0s+1][k0s];
            acc0.x*=a_dec; acc0.y*=a_dec; acc0.z*=a_dec; acc0.w*=a_dec;
            acc1.x*=a_dec; acc1.y*=a_dec; acc1.z*=a_dec; acc1.w*=a_dec;
            for (int r = 0; r < 64; ++r) {
                float2 vv = *(float2*)&vn[r][w0s];
                float4 kv = *(float4*)&kd[r][k0s];
                acc0.x += vv.x*kv.x; acc0.y += vv.x*kv.y; acc0.z += vv.x*kv.z; acc0.w += vv.x*kv.w;
                acc1.x += vv.y*kv.x; acc1.y += vv.y*kv.y; acc1.z += vv.y*kv.z; acc1.w += vv.y*kv.w;
            }
            *(float4*)&stT[w0s][k0s]   = acc0;
            *(float4*)&stT[w0s+1][k0s] = acc1;
        }
        __syncthreads();
    }
}

// ---------------- Phase 3: outputs, fully parallel (4096 blocks = chunk x Dv-half) ----------------
__global__ __launch_bounds__(256) void dr_phase3(
    const float* __restrict__ Q,
    const unsigned short* __restrict__ Uw, const unsigned short* __restrict__ KCDw,
    const unsigned short* __restrict__ ATTNw, const unsigned short* __restrict__ STw,
    const float* __restrict__ RQw, float* __restrict__ Out)
{
    __shared__ float qg[64][132];    // q_norm*scale*exp(gcs)
    __shared__ float kc[64][132];    // kcd
    __shared__ float STl[64][132];   // state^T rows for this v-half: STl[v][k]
    __shared__ float at[64][68];     // attn (masked)
    __shared__ float vnT[64][68];    // v_new^T: vnT[v][r]

    const int tid = threadIdx.x;
    const int half = blockIdx.x & 1;
    const int cid = blockIdx.x >> 1;
    const int n = cid & (NC_-1), bh = cid >> 6;
    const int h = bh & (H_-1), b = bh >> 4;
    const int rowbase = (b*S_ + n*CK_)*H_ + h;
    const int vbase = half*64;

    #pragma unroll
    for (int i = 0; i < 8; ++i) {
        int idx4 = tid + 256*i;
        int r = idx4 >> 5, c0 = (idx4 & 31)*4;
        float rq = RQw[cid*64 + r];
        float4 qv = *(const float4*)(Q + (size_t)(rowbase + r*H_)*DK_ + c0);
        qv.x *= rq; qv.y *= rq; qv.z *= rq; qv.w *= rq;
        *(float4*)&qg[r][c0] = qv;
        uint2 kcv = ((const uint2*)(KCDw + (size_t)cid*8192))[idx4];
        float4 f;
        f.x = bf2f((unsigned short)(kcv.x & 0xffff));
        f.y = bf2f((unsigned short)(kcv.x >> 16));
        f.z = bf2f((unsigned short)(kcv.y & 0xffff));
        f.w = bf2f((unsigned short)(kcv.y >> 16));
        *(float4*)&kc[r][c0] = f;
        uint2 stv = ((const uint2*)(STw + ((size_t)cid*128 + vbase)*128))[idx4];
        float4 g;
        g.x = bf2f((unsigned short)(stv.x & 0xffff));
        g.y = bf2f((unsigned short)(stv.x >> 16));
        g.z = bf2f((unsigned short)(stv.y & 0xffff));
        g.w = bf2f((unsigned short)(stv.y >> 16));
        *(float4*)&STl[r][c0] = g;
    }
    #pragma unroll
    for (int i = 0; i < 4; ++i) {
        int idx4 = tid + 256*i;
        int r = idx4 >> 4, j0 = (idx4 & 15)*4;
        uint2 av = ((const uint2*)(ATTNw + (size_t)cid*4096))[idx4];
        at[r][j0]   = bf2f((unsigned short)(av.x & 0xffff));
        at[r][j0+1] = bf2f((unsigned short)(av.x >> 16));
        at[r][j0+2] = bf2f((unsigned short)(av.y & 0xffff));
        at[r][j0+3] = bf2f((unsigned short)(av.y >> 16));
    }
    __syncthreads();

    const int r0 = (tid & 15)*4, v4 = (tid >> 4)*4;

    // vn = u - kc @ state  (computed transposed: vnT[v][r])
    {
        float4 acc[4];   // acc[x] components = v offsets 0..3, row r0+x
        #pragma unroll
        for (int x = 0; x < 4; ++x) {
            ushort4 uv = *(const ushort4*)(Uw + (size_t)cid*8192 + (r0+x)*128 + vbase + v4);
            acc[x].x = bf2f(uv.x); acc[x].y = bf2f(uv.y); acc[x].z = bf2f(uv.z); acc[x].w = bf2f(uv.w);
        }
        for (int k0 = 0; k0 < 128; k0 += 4) {
            float4 ar[4], bv[4];
            #pragma unroll
            for (int x = 0; x < 4; ++x) ar[x] = *(float4*)&kc[r0+x][k0];
            #pragma unroll
            for (int y = 0; y < 4; ++y) bv[y] = *(float4*)&STl[v4+y][k0];
            #pragma unroll
            for (int x = 0; x < 4; ++x) {
                acc[x].x -= DOT4(ar[x], bv[0]);
                acc[x].y -= DOT4(ar[x], bv[1]);
                acc[x].z -= DOT4(ar[x], bv[2]);
                acc[x].w -= DOT4(ar[x], bv[3]);
            }
        }
        #pragma unroll
        for (int x = 0; x < 4; ++x) {
            vnT[v4][r0+x]   = acc[x].x;
            vnT[v4+1][r0+x] = acc[x].y;
            vnT[v4+2][r0+x] = acc[x].z;
            vnT[v4+3][r0+x] = acc[x].w;
        }
    }
    __syncthreads();

    // o = qg @ state + attn @ vn
    {
        float4 acc[4] = {};
        for (int k0 = 0; k0 < 128; k0 += 4) {
            float4 ar[4], bv[4];
            #pragma unroll
            for (int x = 0; x < 4; ++x) ar[x] = *(float4*)&qg[r0+x][k0];
            #pragma unroll
            for (int y = 0; y < 4; ++y) bv[y] = *(float4*)&STl[v4+y][k0];
            #pragma unroll
            for (int x = 0; x < 4; ++x) {
                acc[x].x += DOT4(ar[x], bv[0]);
                acc[x].y += DOT4(ar[x], bv[1]);
                acc[x].z += DOT4(ar[x], bv[2]);
                acc[x].w += DOT4(ar[x], bv[3]);
            }
        }
        for (int j0 = 0; j0 < 64; j0 += 4) {
            float4 ar[4], bv[4];
            #pragma unroll
            for (int x = 0; x < 4; ++x) ar[x] = *(float4*)&at[r0+x][j0];
            #pragma unroll
            for (int y = 0; y < 4; ++y) bv[y] = *(float4*)&vnT[v4+y][j0];
            #pragma unroll
            for (int x = 0; x < 4; ++x) {
                acc[x].x += DOT4(ar[x], bv[0]);
                acc[x].y += DOT4(ar[x], bv[1]);
                acc[x].z += DOT4(ar[x], bv[2]);
                acc[x].w += DOT4(ar[x], bv[3]);
            }
        }
        #pragma unroll
        for (int x = 0; x < 4; ++x)
            *(float4*)(Out + (size_t)(rowbase + (r0+x)*H_)*DV_ + vbase + v4) = acc[x];
    }
}

extern "C" void kernel_launch(void* const* d_in, const int* in_sizes, int n_in,
                              void* d_out, int out_size, void* d_ws, size_t ws_size,
                              hipStream_t stream) {
    (void)in_sizes; (void)n_in; (void)out_size; (void)ws_size;
    const float* Q  = (const float*)d_in[0];
    const float* K  = (const float*)d_in[1];
    const float* V  = (const float*)d_in[2];
    const float* G  = (const float*)d_in[3];
    const float* Bt = (const float*)d_in[4];
    float* Out = (float*)d_out;

    // ws layout: U bf16 | KCD bf16 | ATTN bf16 | ST bf16 | RQ f32 | RK f32 | EG f32  = ~152 MB
    unsigned short* Uw    = (unsigned short*)d_ws;
    unsigned short* KCDw  = Uw    + (size_t)2048*64*128;
    unsigned short* ATTNw = KCDw  + (size_t)2048*64*128;
    unsigned short* STw   = ATTNw + (size_t)2048*64*64;
    float* RQw = (float*)(STw + (size_t)2048*128*128);
    float* RKw = RQw + 2048*64;
    float* EGw = RKw + 2048*64;

    dr_phase1<<<2048, 256, 0, stream>>>(Q, K, V, G, Bt, Uw, KCDw, ATTNw, RQw, RKw, EGw);
    dr_phase2<<<256, 256, 0, stream>>>(K, Uw, KCDw, RKw, EGw, STw);
    dr_phase3<<<4096, 256, 0, stream>>>(Q, Uw, KCDw, ATTNw, STw, RQw, Out);
}

// Round 2
// 853.050 us; speedup vs baseline: 1.4378x; 1.1329x over previous
//
#include <hip/hip_runtime.h>
#include <hip/hip_fp16.h>

#define B_   2
#define S_   4096
#define H_   16
#define DK_  128
#define DV_  128
#define CK_  64
#define NC_  (S_/CK_)            // 64 chunks per sequence
#define QSCALE 0.08838834764831845f   // 128^-0.5

#define DOT4(a,b) ((a).x*(b).x + (a).y*(b).y + (a).z*(b).z + (a).w*(b).w)

// 16B-granule XOR swizzles: kill 8-way bank conflicts on multi-row reads.
// SWH: arrays of 16-bit elems (granule = 8 elems). SWV: f32 arrays (granule = 4 elems).
#define SWH(c, r) (((((c) >> 3) ^ (((r) >> 2) & 7)) << 3) | ((c) & 7))
#define SWV(c, r) (((((c) >> 2) ^ (((r) >> 2) & 7)) << 2) | ((c) & 3))

static __device__ __forceinline__ unsigned short f2bf(float x) {
    unsigned u = __float_as_uint(x);
    unsigned r = u + 0x7fffu + ((u >> 16) & 1u);
    return (unsigned short)(r >> 16);
}
static __device__ __forceinline__ float bf2f(unsigned short h) {
    return __uint_as_float(((unsigned)h) << 16);
}
static __device__ __forceinline__ float4 h4tof4(const __half* p) {
    float2 f01 = __half22float2(*(const __half2*)p);
    float2 f23 = __half22float2(*(const __half2*)(p + 2));
    return make_float4(f01.x, f01.y, f23.x, f23.y);
}
static __device__ __forceinline__ void f4toh4(__half* p, float4 v) {
    *(__half2*)p       = __floats2half2_rn(v.x, v.y);
    *(__half2*)(p + 2) = __floats2half2_rn(v.z, v.w);
}

struct f8 { float4 lo, hi; };
// 8 bf16 (uint4) -> 8 f32: 2 VALU ops per uint (shl / and)
static __device__ __forceinline__ f8 unp_bf16x8(uint4 u) {
    f8 r;
    r.lo.x = __uint_as_float(u.x << 16); r.lo.y = __uint_as_float(u.x & 0xffff0000u);
    r.lo.z = __uint_as_float(u.y << 16); r.lo.w = __uint_as_float(u.y & 0xffff0000u);
    r.hi.x = __uint_as_float(u.z << 16); r.hi.y = __uint_as_float(u.z & 0xffff0000u);
    r.hi.z = __uint_as_float(u.w << 16); r.hi.w = __uint_as_float(u.w & 0xffff0000u);
    return r;
}
static __device__ __forceinline__ f8 unp_f16x8(uint4 u) {
    f8 r;
    float2 a = __half22float2(*(__half2*)&u.x), b = __half22float2(*(__half2*)&u.y);
    float2 c = __half22float2(*(__half2*)&u.z), d = __half22float2(*(__half2*)&u.w);
    r.lo = make_float4(a.x, a.y, b.x, b.y);
    r.hi = make_float4(c.x, c.y, d.x, d.y);
    return r;
}

// ---------------- Phase 1: per-chunk (parallel over 2048 chunks) ----------------
// (unchanged from previous round)
__global__ __launch_bounds__(256) void dr_phase1(
    const float* __restrict__ Q, const float* __restrict__ K,
    const float* __restrict__ V, const float* __restrict__ G,
    const float* __restrict__ Bt,
    unsigned short* __restrict__ Uw, unsigned short* __restrict__ KCDw,
    unsigned short* __restrict__ ATTNw,
    float* __restrict__ RQw, float* __restrict__ RKw, float* __restrict__ EGw)
{
    __shared__ float kn[64][132];                 // raw k, swizzled
    __shared__ __align__(16) __half bufh[64][136]; // v*beta, then raw q (f16)
    __shared__ float T[64][68];
    __shared__ float tmp[32][36];                 // blocked-inverse scratch
    __shared__ float bet[64], rn[64], epos[64], eneg[64], cL[64], cR[64];

    const int tid = threadIdx.x;
    const int cid = blockIdx.x;
    const int n   = cid & (NC_ - 1);
    const int bh  = cid >> 6;
    const int h   = bh & (H_ - 1);
    const int b   = bh >> 4;
    const int rowbase = (b*S_ + n*CK_)*H_ + h;

    // A: stage raw K (swizzled); wave0: shfl-scan of g, exps, beta
    #pragma unroll
    for (int i = 0; i < 8; ++i) {
        int idx4 = tid + 256*i;
        int r = idx4 >> 5, c0 = (idx4 & 31) << 2;
        *(float4*)&kn[r][c0 ^ (r & 28)] =
            *(const float4*)(K + (size_t)(rowbase + r*H_)*DK_ + c0);
    }
    if (tid < 64) {
        float g = G[rowbase + tid*H_];
        #pragma unroll
        for (int off = 1; off < 64; off <<= 1) {
            float o = __shfl_up(g, off, 64);
            if (tid >= off) g += o;
        }
        float ep = expf(g);
        epos[tid] = ep;
        eneg[tid] = expf(-g);
        bet[tid]  = Bt[rowbase + tid*H_];
        if (tid == 63) EGw[cid] = ep;
    }
    __syncthreads();

    // B: stage v*beta -> f16; k row norms -> rn, cL, cR, RK
    #pragma unroll
    for (int i = 0; i < 8; ++i) {
        int idx4 = tid + 256*i;
        int r = idx4 >> 5, c0 = (idx4 & 31) << 2;
        float bb = bet[r];
        float4 vv = *(const float4*)(V + (size_t)(rowbase + r*H_)*DV_ + c0);
        vv.x *= bb; vv.y *= bb; vv.z *= bb; vv.w *= bb;
        f4toh4(&bufh[r][c0], vv);
    }
    if (tid < 64) {
        const int xr = tid & 28;
        float s = 0.f;
        #pragma unroll
        for (int c = 0; c < 128; c += 4) { float4 x = *(float4*)&kn[tid][c ^ xr]; s += DOT4(x,x); }
        float r_ = rsqrtf(s + 1e-6f);
        rn[tid] = r_;
        RKw[cid*64 + tid] = r_*epos[63]*eneg[tid];
        cL[tid] = bet[tid]*epos[tid]*r_;
        cR[tid] = eneg[tid]*r_;
    }
    __syncthreads();

    // C: T = -strict_lower( cL(i)*cR(j) * (kraw_i . kraw_j) )
    {
        const int i0 = (tid >> 4) << 2, j0 = (tid & 15) << 2;
        const int xi = i0 & 28, xj = j0 & 28;
        float acc[4][4] = {};
        if (j0 <= i0) {
            for (int c = 0; c < 128; c += 4) {
                float4 a0 = *(float4*)&kn[i0  ][c ^ xi], a1 = *(float4*)&kn[i0+1][c ^ xi];
                float4 a2 = *(float4*)&kn[i0+2][c ^ xi], a3 = *(float4*)&kn[i0+3][c ^ xi];
                float4 b0 = *(float4*)&kn[j0  ][c ^ xj], b1 = *(float4*)&kn[j0+1][c ^ xj];
                float4 b2 = *(float4*)&kn[j0+2][c ^ xj], b3 = *(float4*)&kn[j0+3][c ^ xj];
                acc[0][0]+=DOT4(a0,b0); acc[0][1]+=DOT4(a0,b1); acc[0][2]+=DOT4(a0,b2); acc[0][3]+=DOT4(a0,b3);
                acc[1][0]+=DOT4(a1,b0); acc[1][1]+=DOT4(a1,b1); acc[1][2]+=DOT4(a1,b2); acc[1][3]+=DOT4(a1,b3);
                acc[2][0]+=DOT4(a2,b0); acc[2][1]+=DOT4(a2,b1); acc[2][2]+=DOT4(a2,b2); acc[2][3]+=DOT4(a2,b3);
                acc[3][0]+=DOT4(a3,b0); acc[3][1]+=DOT4(a3,b1); acc[3][2]+=DOT4(a3,b2); acc[3][3]+=DOT4(a3,b3);
            }
        }
        #pragma unroll
        for (int x = 0; x < 4; ++x) {
            float fi = cL[i0+x];
            #pragma unroll
            for (int y = 0; y < 4; ++y) {
                int i = i0+x, j = j0+y;
                T[i][j] = (i > j) ? (-fi*cR[j]*acc[x][y]) : 0.f;
            }
        }
    }
    __syncthreads();

    // D1: copy diagonal 16x16 blocks (original -A) into tmp
    {
        float* tf = &tmp[0][0];
        for (int t = tid; t < 1024; t += 256) {
            int d = t >> 8, i = (t >> 4) & 15, j = t & 15;
            tf[t] = T[(d<<4) + i][(d<<4) + j];
        }
    }
    __syncthreads();
    // D2: invert each diagonal block in place, one thread per (block, column)
    if (tid < 64) {
        const float* Ad = &tmp[0][0] + ((tid >> 4) << 8);
        const int j = tid & 15, R = (tid >> 4) << 4;
        for (int i = j+1; i < 16; ++i) {
            float x = Ad[(i<<4) + j];
            for (int l = j+1; l < i; ++l) x += Ad[(i<<4) + l] * T[R+l][R+j];
            T[R+i][R+j] = x;
        }
    }
    __syncthreads();
    // D3: 16 -> 32 (two pairs). X21 = (I+X22) * T21 * (I+X11)
    {
        const int p = tid >> 7, rem = tid & 127, i = rem >> 3, j0 = (rem & 7) << 1;
        const int bb2 = p << 5;
        float x0 = T[bb2+16+i][bb2+j0], x1 = T[bb2+16+i][bb2+j0+1];
        for (int l = j0+1; l < 16; ++l) {
            float a = T[bb2+16+i][bb2+l];
            x0 += a * T[bb2+l][bb2+j0];
            if (l > j0+1) x1 += a * T[bb2+l][bb2+j0+1];
        }
        tmp[(p<<4)+i][j0] = x0; tmp[(p<<4)+i][j0+1] = x1;
        __syncthreads();
        float y0 = tmp[(p<<4)+i][j0], y1 = tmp[(p<<4)+i][j0+1];
        for (int l = 0; l < i; ++l) {
            float a = T[bb2+16+i][bb2+16+l];
            y0 += a * tmp[(p<<4)+l][j0];
            y1 += a * tmp[(p<<4)+l][j0+1];
        }
        T[bb2+16+i][bb2+j0] = y0; T[bb2+16+i][bb2+j0+1] = y1;
    }
    __syncthreads();
    // D4: 32 -> 64
    {
        const int i = tid >> 3, j0 = (tid & 7) << 2;
        float x0 = T[32+i][j0], x1 = T[32+i][j0+1], x2 = T[32+i][j0+2], x3 = T[32+i][j0+3];
        for (int l = j0+1; l < 32; ++l) {
            float a = T[32+i][l];
            x0 += a * T[l][j0];
            if (l > j0+1) x1 += a * T[l][j0+1];
            if (l > j0+2) x2 += a * T[l][j0+2];
            if (l > j0+3) x3 += a * T[l][j0+3];
        }
        tmp[i][j0] = x0; tmp[i][j0+1] = x1; tmp[i][j0+2] = x2; tmp[i][j0+3] = x3;
        __syncthreads();
        float y0 = tmp[i][j0], y1 = tmp[i][j0+1], y2 = tmp[i][j0+2], y3 = tmp[i][j0+3];
        for (int l = 0; l < i; ++l) {
            float a = T[32+i][32+l];
            y0 += a * tmp[l][j0];   y1 += a * tmp[l][j0+1];
            y2 += a * tmp[l][j0+2]; y3 += a * tmp[l][j0+3];
        }
        T[32+i][j0] = y0; T[32+i][j0+1] = y1; T[32+i][j0+2] = y2; T[32+i][j0+3] = y3;
    }
    __syncthreads();

    // E: U = (I+T) @ (v*beta),  KCD = (I+T) @ (k*beta*exp(gcs))  -> bf16
    {
        unsigned short* Up = Uw + (size_t)cid*(CK_*DV_);
        for (int tt = tid; tt < 512; tt += 256) {
            const int i0 = (tt >> 5) << 2, c0 = (tt & 31) << 2;
            float4 acc[4];
            #pragma unroll
            for (int x = 0; x < 4; ++x) acc[x] = h4tof4(&bufh[i0+x][c0]);
            for (int j0 = 0; j0 <= i0; j0 += 4) {
                float4 t0 = *(float4*)&T[i0][j0],   t1 = *(float4*)&T[i0+1][j0];
                float4 t2 = *(float4*)&T[i0+2][j0], t3 = *(float4*)&T[i0+3][j0];
                float4 b0 = h4tof4(&bufh[j0][c0]),   b1 = h4tof4(&bufh[j0+1][c0]);
                float4 b2 = h4tof4(&bufh[j0+2][c0]), b3 = h4tof4(&bufh[j0+3][c0]);
                acc[0].x += t0.x*b0.x + t0.y*b1.x + t0.z*b2.x + t0.w*b3.x;
                acc[0].y += t0.x*b0.y + t0.y*b1.y + t0.z*b2.y + t0.w*b3.y;
                acc[0].z += t0.x*b0.z + t0.y*b1.z + t0.z*b2.z + t0.w*b3.z;
                acc[0].w += t0.x*b0.w + t0.y*b1.w + t0.z*b2.w + t0.w*b3.w;
                acc[1].x += t1.x*b0.x + t1.y*b1.x + t1.z*b2.x + t1.w*b3.x;
                acc[1].y += t1.x*b0.y + t1.y*b1.y + t1.z*b2.y + t1.w*b3.y;
                acc[1].z += t1.x*b0.z + t1.y*b1.z + t1.z*b2.z + t1.w*b3.z;
                acc[1].w += t1.x*b0.w + t1.y*b1.w + t1.z*b2.w + t1.w*b3.w;
                acc[2].x += t2.x*b0.x + t2.y*b1.x + t2.z*b2.x + t2.w*b3.x;
                acc[2].y += t2.x*b0.y + t2.y*b1.y + t2.z*b2.y + t2.w*b3.y;
                acc[2].z += t2.x*b0.z + t2.y*b1.z + t2.z*b2.z + t2.w*b3.z;
                acc[2].w += t2.x*b0.w + t2.y*b1.w + t2.z*b2.w + t2.w*b3.w;
                acc[3].x += t3.x*b0.x + t3.y*b1.x + t3.z*b2.x + t3.w*b3.x;
                acc[3].y += t3.x*b0.y + t3.y*b1.y + t3.z*b2.y + t3.w*b3.y;
                acc[3].z += t3.x*b0.z + t3.y*b1.z + t3.z*b2.z + t3.w*b3.z;
                acc[3].w += t3.x*b0.w + t3.y*b1.w + t3.z*b2.w + t3.w*b3.w;
            }
            #pragma unroll
            for (int x = 0; x < 4; ++x) {
                ushort4 o; o.x = f2bf(acc[x].x); o.y = f2bf(acc[x].y);
                o.z = f2bf(acc[x].z); o.w = f2bf(acc[x].w);
                *(ushort4*)(Up + (i0+x)*DV_ + c0) = o;
            }
        }
        unsigned short* Kp = KCDw + (size_t)cid*(CK_*DK_);
        for (int tt = tid; tt < 512; tt += 256) {
            const int i0 = (tt >> 5) << 2, c0 = (tt & 31) << 2;
            const int xi = i0 & 28;
            float4 acc[4];
            #pragma unroll
            for (int x = 0; x < 4; ++x) {
                float wi = cL[i0+x];
                float4 kv = *(float4*)&kn[i0+x][c0 ^ xi];
                acc[x].x = kv.x*wi; acc[x].y = kv.y*wi; acc[x].z = kv.z*wi; acc[x].w = kv.w*wi;
            }
            for (int j0 = 0; j0 <= i0; j0 += 4) {
                const int xj = j0 & 28;
                float w0 = cL[j0], w1 = cL[j0+1], w2 = cL[j0+2], w3 = cL[j0+3];
                float4 t0 = *(float4*)&T[i0][j0],   t1 = *(float4*)&T[i0+1][j0];
                float4 t2 = *(float4*)&T[i0+2][j0], t3 = *(float4*)&T[i0+3][j0];
                float4 b0 = *(float4*)&kn[j0  ][c0 ^ xj], b1 = *(float4*)&kn[j0+1][c0 ^ xj];
                float4 b2 = *(float4*)&kn[j0+2][c0 ^ xj], b3 = *(float4*)&kn[j0+3][c0 ^ xj];
                b0.x*=w0; b0.y*=w0; b0.z*=w0; b0.w*=w0;
                b1.x*=w1; b1.y*=w1; b1.z*=w1; b1.w*=w1;
                b2.x*=w2; b2.y*=w2; b2.z*=w2; b2.w*=w2;
                b3.x*=w3; b3.y*=w3; b3.z*=w3; b3.w*=w3;
                acc[0].x += t0.x*b0.x + t0.y*b1.x + t0.z*b2.x + t0.w*b3.x;
                acc[0].y += t0.x*b0.y + t0.y*b1.y + t0.z*b2.y + t0.w*b3.y;
                acc[0].z += t0.x*b0.z + t0.y*b1.z + t0.z*b2.z + t0.w*b3.z;
                acc[0].w += t0.x*b0.w + t0.y*b1.w + t0.z*b2.w + t0.w*b3.w;
                acc[1].x += t1.x*b0.x + t1.y*b1.x + t1.z*b2.x + t1.w*b3.x;
                acc[1].y += t1.x*b0.y + t1.y*b1.y + t1.z*b2.y + t1.w*b3.y;
                acc[1].z += t1.x*b0.z + t1.y*b1.z + t1.z*b2.z + t1.w*b3.z;
                acc[1].w += t1.x*b0.w + t1.y*b1.w + t1.z*b2.w + t1.w*b3.w;
                acc[2].x += t2.x*b0.x + t2.y*b1.x + t2.z*b2.x + t2.w*b3.x;
                acc[2].y += t2.x*b0.y + t2.y*b1.y + t2.z*b2.y + t2.w*b3.y;
                acc[2].z += t2.x*b0.z + t2.y*b1.z + t2.z*b2.z + t2.w*b3.z;
                acc[2].w += t2.x*b0.w + t2.y*b1.w + t2.z*b2.w + t2.w*b3.w;
                acc[3].x += t3.x*b0.x + t3.y*b1.x + t3.z*b2.x + t3.w*b3.x;
                acc[3].y += t3.x*b0.y + t3.y*b1.y + t3.z*b2.y + t3.w*b3.y;
                acc[3].z += t3.x*b0.z + t3.y*b1.z + t3.z*b2.z + t3.w*b3.z;
                acc[3].w += t3.x*b0.w + t3.y*b1.w + t3.z*b2.w + t3.w*b3.w;
            }
            #pragma unroll
            for (int x = 0; x < 4; ++x) {
                ushort4 o; o.x = f2bf(acc[x].x); o.y = f2bf(acc[x].y);
                o.z = f2bf(acc[x].z); o.w = f2bf(acc[x].w);
                *(ushort4*)(Kp + (i0+x)*DK_ + c0) = o;
            }
        }
    }
    __syncthreads();

    // F: stage raw q -> f16 (scale folded into epilogue)
    #pragma unroll
    for (int i = 0; i < 8; ++i) {
        int idx4 = tid + 256*i;
        int r = idx4 >> 5, c0 = (idx4 & 31) << 2;
        f4toh4(&bufh[r][c0], *(const float4*)(Q + (size_t)(rowbase + r*H_)*DK_ + c0));
    }
    __syncthreads();
    // G: q row norms (QSCALE folded); RQ
    if (tid < 64) {
        float s = 0.f;
        #pragma unroll
        for (int c = 0; c < 128; c += 4) { float4 x = h4tof4(&bufh[tid][c]); s += DOT4(x,x); }
        float r_ = rsqrtf(s + 1e-6f)*QSCALE;
        rn[tid] = r_;
        RQw[cid*64 + tid] = r_*epos[tid];
    }
    __syncthreads();

    // H: attn = tril(q@k^T * decay) -> bf16
    {
        unsigned short* Ap = ATTNw + (size_t)cid*(CK_*CK_);
        const int i0 = (tid >> 4) << 2, j0 = (tid & 15) << 2;
        const int xj = j0 & 28;
        float acc[4][4] = {};
        if (j0 <= i0) {
            for (int c = 0; c < 128; c += 4) {
                float4 a0 = h4tof4(&bufh[i0  ][c]), a1 = h4tof4(&bufh[i0+1][c]);
                float4 a2 = h4tof4(&bufh[i0+2][c]), a3 = h4tof4(&bufh[i0+3][c]);
                float4 b0 = *(float4*)&kn[j0  ][c ^ xj], b1 = *(float4*)&kn[j0+1][c ^ xj];
                float4 b2 = *(float4*)&kn[j0+2][c ^ xj], b3 = *(float4*)&kn[j0+3][c ^ xj];
                acc[0][0]+=DOT4(a0,b0); acc[0][1]+=DOT4(a0,b1); acc[0][2]+=DOT4(a0,b2); acc[0][3]+=DOT4(a0,b3);
                acc[1][0]+=DOT4(a1,b0); acc[1][1]+=DOT4(a1,b1); acc[1][2]+=DOT4(a1,b2); acc[1][3]+=DOT4(a1,b3);
                acc[2][0]+=DOT4(a2,b0); acc[2][1]+=DOT4(a2,b1); acc[2][2]+=DOT4(a2,b2); acc[2][3]+=DOT4(a2,b3);
                acc[3][0]+=DOT4(a3,b0); acc[3][1]+=DOT4(a3,b1); acc[3][2]+=DOT4(a3,b2); acc[3][3]+=DOT4(a3,b3);
            }
        }
        #pragma unroll
        for (int x = 0; x < 4; ++x) {
            ushort4 o;
            int i = i0+x;
            float fi = rn[i]*epos[i];
            float v0 = (j0   <= i) ? acc[x][0]*fi*cR[j0]   : 0.f;
            float v1 = (j0+1 <= i) ? acc[x][1]*fi*cR[j0+1] : 0.f;
            float v2 = (j0+2 <= i) ? acc[x][2]*fi*cR[j0+2] : 0.f;
            float v3 = (j0+3 <= i) ? acc[x][3]*fi*cR[j0+3] : 0.f;
            o.x = f2bf(v0); o.y = f2bf(v1); o.z = f2bf(v2); o.w = f2bf(v3);
            *(ushort4*)(Ap + i*CK_ + j0) = o;
        }
    }
}

// ---------------- Phase 2: state recurrence (256 blocks = bh x 8 v-slices) ----------------
// 512 threads (8 waves/CU) + register prefetch of next chunk's K/KCD/RK/U:
// HBM latency hides under vn+update compute instead of serializing.
#define P2_LOAD(nn) do { \
    const int cid_ = bh*NC_ + (nn); \
    const int rb_ = (b*S_ + (nn)*CK_)*H_ + h; \
    _Pragma("unroll") \
    for (int i = 0; i < 4; ++i) { \
        int idx4 = tid + 512*i; \
        int r = idx4 >> 5, c0 = (idx4 & 31)*4; \
        pk[i]  = *(const float4*)(K + (size_t)(rb_ + r*H_)*DK_ + c0); \
        pc[i]  = ((const uint2*)(KCDw + (size_t)cid_*8192))[idx4]; \
        prk[i] = RKw[cid_*64 + r]; \
    } \
    pu = *(const unsigned*)(Uw + (size_t)cid_*8192 + rg*128 + v0 + w0v); \
} while(0)

__global__ __launch_bounds__(512) void dr_phase2(
    const float* __restrict__ K,
    const unsigned short* __restrict__ Uw, const unsigned short* __restrict__ KCDw,
    const float* __restrict__ RKw, const float* __restrict__ EGw,
    unsigned short* __restrict__ STw)
{
    __shared__ float kc[64][132];    // kcd fp32
    __shared__ float kd[64][132];    // k_norm * exp(g_last - gcs)
    __shared__ float stT[16][132];   // state^T slice: stT[v][k]
    __shared__ float vn[64][20];     // v_new slice

    const int tid = threadIdx.x;
    const int vs = blockIdx.x & 7, bh = blockIdx.x >> 3;
    const int h = bh & (H_-1), b = bh >> 4;
    const int v0 = vs*16;

    for (int i = tid; i < 16*132; i += 512) (&stT[0][0])[i] = 0.f;

    const int rg  = tid >> 3;            // vn row (0..63)
    const int w0v = (tid & 7) * 2;       // vn col pair (0..14)
    const int wq  = tid >> 5;            // state row (0..15)
    const int k0s = (tid & 31) * 4;      // state col quad
    const int srow = tid >> 5, scol = (tid & 31) * 4;   // ST store map

    float4 pk[4]; uint2 pc[4]; float prk[4]; unsigned pu;
    P2_LOAD(0);
    __syncthreads();

    for (int n = 0; n < NC_; ++n) {
        const int cid = bh*NC_ + n;

        // write prefetched chunk n into LDS
        #pragma unroll
        for (int i = 0; i < 4; ++i) {
            int idx4 = tid + 512*i;
            int r = idx4 >> 5, c0 = (idx4 & 31)*4;
            float4 f;
            f.x = bf2f((unsigned short)(pc[i].x & 0xffff));
            f.y = bf2f((unsigned short)(pc[i].x >> 16));
            f.z = bf2f((unsigned short)(pc[i].y & 0xffff));
            f.w = bf2f((unsigned short)(pc[i].y >> 16));
            *(float4*)&kc[r][c0] = f;
            float4 kv = pk[i];
            kv.x *= prk[i]; kv.y *= prk[i]; kv.z *= prk[i]; kv.w *= prk[i];
            *(float4*)&kd[r][c0] = kv;
        }
        const float u0 = bf2f((unsigned short)(pu & 0xffff));
        const float u1 = bf2f((unsigned short)(pu >> 16));

        // store state entering chunk n (pre-update) for phase 3
        {
            float4 s = *(float4*)&stT[srow][scol];
            ushort4 p;
            p.x=f2bf(s.x); p.y=f2bf(s.y); p.z=f2bf(s.z); p.w=f2bf(s.w);
            *(ushort4*)(STw + ((size_t)cid*128 + v0 + srow)*128 + scol) = p;
        }
        __syncthreads();

        if (n+1 < NC_) P2_LOAD(n+1);    // overlap HBM latency with compute below
        const float a_dec = EGw[cid];

        // vn = u - kc @ stT^T   (1 row x 2 cols per thread)
        {
            float s0 = u0, s1 = u1;
            for (int k0 = 0; k0 < 128; k0 += 4) {
                float4 a  = *(float4*)&kc[rg][k0];
                float4 b0 = *(float4*)&stT[w0v][k0];
                float4 b1 = *(float4*)&stT[w0v+1][k0];
                s0 -= DOT4(a,b0); s1 -= DOT4(a,b1);
            }
            vn[rg][w0v] = s0; vn[rg][w0v+1] = s1;
        }
        __syncthreads();

        // stT = a*stT + vn^T @ kd   (1 row x 4 cols per thread, in place)
        {
            float4 acc = *(float4*)&stT[wq][k0s];
            acc.x*=a_dec; acc.y*=a_dec; acc.z*=a_dec; acc.w*=a_dec;
            for (int r = 0; r < 64; ++r) {
                float vv = vn[r][wq];
                float4 kv = *(float4*)&kd[r][k0s];
                acc.x += vv*kv.x; acc.y += vv*kv.y; acc.z += vv*kv.z; acc.w += vv*kv.w;
            }
            *(float4*)&stT[wq][k0s] = acc;
        }
        __syncthreads();
    }
}

// ---------------- Phase 3: outputs (4096 blocks = chunk x Dv-half) ----------------
// LDS 78.8 KB -> 2 blocks/CU. bf16 operands stay bf16 in LDS (unpack at use);
// q as f16; vnT f32. 16B-granule XOR swizzle on all multi-row-read arrays.
__global__ __launch_bounds__(256) void dr_phase3(
    const float* __restrict__ Q,
    const unsigned short* __restrict__ Uw, const unsigned short* __restrict__ KCDw,
    const unsigned short* __restrict__ ATTNw, const unsigned short* __restrict__ STw,
    const float* __restrict__ RQw, float* __restrict__ Out)
{
    __shared__ __align__(16) __half         qh[64][136];  // q*rq*exp(gcs) (f16, swz)
    __shared__ __align__(16) unsigned short kch[64][136]; // kcd bf16 raw (swz)
    __shared__ __align__(16) unsigned short sth[64][136]; // state^T bf16 raw (swz)
    __shared__ __align__(16) unsigned short ath[64][72];  // attn bf16 raw (swz)
    __shared__ float vnT[64][68];                         // v_new^T f32 (swz)

    const int tid = threadIdx.x;
    const int half = blockIdx.x & 1;
    const int cid = blockIdx.x >> 1;
    const int n = cid & (NC_-1), bh = cid >> 6;
    const int h = bh & (H_-1), b = bh >> 4;
    const int rowbase = (b*S_ + n*CK_)*H_ + h;
    const int vbase = half*64;

    #pragma unroll
    for (int i = 0; i < 8; ++i) {
        int idx4 = tid + 256*i;
        int r = idx4 >> 5, c0 = (idx4 & 31)*4;
        float rq = RQw[cid*64 + r];
        float4 qv = *(const float4*)(Q + (size_t)(rowbase + r*H_)*DK_ + c0);
        qv.x *= rq; qv.y *= rq; qv.z *= rq; qv.w *= rq;
        f4toh4(&qh[r][SWH(c0, r)], qv);
        uint2 kcv = ((const uint2*)(KCDw + (size_t)cid*8192))[idx4];
        *(uint2*)&kch[r][SWH(c0, r)] = kcv;
        uint2 stv = ((const uint2*)(STw + ((size_t)cid*128 + vbase)*128))[idx4];
        *(uint2*)&sth[r][SWH(c0, r)] = stv;
    }
    #pragma unroll
    for (int i = 0; i < 4; ++i) {
        int idx4 = tid + 256*i;
        int r = idx4 >> 4, j0 = (idx4 & 15)*4;
        uint2 av = ((const uint2*)(ATTNw + (size_t)cid*4096))[idx4];
        *(uint2*)&ath[r][SWH(j0, r)] = av;
    }
    __syncthreads();

    // r0 wave-correlated (tid>>4) so the triangular attn loop bound is nearly
    // wave-uniform; v4 on tid&15 makes Out stores 256B-contiguous per wave.
    const int r0 = (tid >> 4)*4, v4 = (tid & 15)*4;

    // vn = u - kc @ state  -> vnT[v][r] (f32, swizzled)
    {
        float4 acc[4];   // acc[x].{x,y,z,w} = vn[r0+x][v4+0..3]
        #pragma unroll
        for (int x = 0; x < 4; ++x) {
            ushort4 uv = *(const ushort4*)(Uw + (size_t)cid*8192 + (r0+x)*128 + vbase + v4);
            acc[x].x = bf2f(uv.x); acc[x].y = bf2f(uv.y); acc[x].z = bf2f(uv.z); acc[x].w = bf2f(uv.w);
        }
        for (int k0 = 0; k0 < 128; k0 += 8) {
            f8 A[4], Bv[4];
            #pragma unroll
            for (int x = 0; x < 4; ++x) A[x]  = unp_bf16x8(*(const uint4*)&kch[r0+x][SWH(k0, r0+x)]);
            #pragma unroll
            for (int y = 0; y < 4; ++y) Bv[y] = unp_bf16x8(*(const uint4*)&sth[v4+y][SWH(k0, v4+y)]);
            #pragma unroll
            for (int x = 0; x < 4; ++x) {
                acc[x].x -= DOT4(A[x].lo, Bv[0].lo) + DOT4(A[x].hi, Bv[0].hi);
                acc[x].y -= DOT4(A[x].lo, Bv[1].lo) + DOT4(A[x].hi, Bv[1].hi);
                acc[x].z -= DOT4(A[x].lo, Bv[2].lo) + DOT4(A[x].hi, Bv[2].hi);
                acc[x].w -= DOT4(A[x].lo, Bv[3].lo) + DOT4(A[x].hi, Bv[3].hi);
            }
        }
        #pragma unroll
        for (int x = 0; x < 4; ++x) {
            vnT[v4+0][SWV(r0+x, v4+0)] = acc[x].x;
            vnT[v4+1][SWV(r0+x, v4+1)] = acc[x].y;
            vnT[v4+2][SWV(r0+x, v4+2)] = acc[x].z;
            vnT[v4+3][SWV(r0+x, v4+3)] = acc[x].w;
        }
    }
    __syncthreads();

    // o = qg @ state + attn @ vn
    {
        float4 acc[4] = {};   // acc[x].{y} = o[r0+x][vbase+v4+y]
        for (int k0 = 0; k0 < 128; k0 += 8) {
            f8 A[4], Bv[4];
            #pragma unroll
            for (int x = 0; x < 4; ++x) A[x]  = unp_f16x8(*(const uint4*)&qh[r0+x][SWH(k0, r0+x)]);
            #pragma unroll
            for (int y = 0; y < 4; ++y) Bv[y] = unp_bf16x8(*(const uint4*)&sth[v4+y][SWH(k0, v4+y)]);
            #pragma unroll
            for (int x = 0; x < 4; ++x) {
                acc[x].x += DOT4(A[x].lo, Bv[0].lo) + DOT4(A[x].hi, Bv[0].hi);
                acc[x].y += DOT4(A[x].lo, Bv[1].lo) + DOT4(A[x].hi, Bv[1].hi);
                acc[x].z += DOT4(A[x].lo, Bv[2].lo) + DOT4(A[x].hi, Bv[2].hi);
                acc[x].w += DOT4(A[x].lo, Bv[3].lo) + DOT4(A[x].hi, Bv[3].hi);
            }
        }
        // attn part: at[i][j]==0 for j>i, so looping whole 8-col granules up to
        // the diagonal granule is safe; bound is wave-correlated via r0.
        for (int j0 = 0; j0 <= r0+3; j0 += 8) {
            f8 A[4];
            #pragma unroll
            for (int x = 0; x < 4; ++x) A[x] = unp_bf16x8(*(const uint4*)&ath[r0+x][SWH(j0, r0+x)]);
            float4 bLo[4], bHi[4];
            #pragma unroll
            for (int y = 0; y < 4; ++y) {
                bLo[y] = *(const float4*)&vnT[v4+y][SWV(j0,   v4+y)];
                bHi[y] = *(const float4*)&vnT[v4+y][SWV(j0+4, v4+y)];
            }
            #pragma unroll
            for (int x = 0; x < 4; ++x) {
                acc[x].x += DOT4(A[x].lo, bLo[0]) + DOT4(A[x].hi, bHi[0]);
                acc[x].y += DOT4(A[x].lo, bLo[1]) + DOT4(A[x].hi, bHi[1]);
                acc[x].z += DOT4(A[x].lo, bLo[2]) + DOT4(A[x].hi, bHi[2]);
                acc[x].w += DOT4(A[x].lo, bLo[3]) + DOT4(A[x].hi, bHi[3]);
            }
        }
        #pragma unroll
        for (int x = 0; x < 4; ++x)
            *(float4*)(Out + (size_t)(rowbase + (r0+x)*H_)*DV_ + vbase + v4) = acc[x];
    }
}

extern "C" void kernel_launch(void* const* d_in, const int* in_sizes, int n_in,
                              void* d_out, int out_size, void* d_ws, size_t ws_size,
                              hipStream_t stream) {
    (void)in_sizes; (void)n_in; (void)out_size; (void)ws_size;
    const float* Q  = (const float*)d_in[0];
    const float* K  = (const float*)d_in[1];
    const float* V  = (const float*)d_in[2];
    const float* G  = (const float*)d_in[3];
    const float* Bt = (const float*)d_in[4];
    float* Out = (float*)d_out;

    // ws layout: U bf16 | KCD bf16 | ATTN bf16 | ST bf16 | RQ f32 | RK f32 | EG f32
    unsigned short* Uw    = (unsigned short*)d_ws;
    unsigned short* KCDw  = Uw    + (size_t)2048*64*128;
    unsigned short* ATTNw = KCDw  + (size_t)2048*64*128;
    unsigned short* STw   = ATTNw + (size_t)2048*64*64;
    float* RQw = (float*)(STw + (size_t)2048*128*128);
    float* RKw = RQw + 2048*64;
    float* EGw = RKw + 2048*64;

    dr_phase1<<<2048, 256, 0, stream>>>(Q, K, V, G, Bt, Uw, KCDw, ATTNw, RQw, RKw, EGw);
    dr_phase2<<<256, 512, 0, stream>>>(K, Uw, KCDw, RKw, EGw, STw);
    dr_phase3<<<4096, 256, 0, stream>>>(Q, Uw, KCDw, ATTNw, STw, RQw, Out);
}